// Round 25
// baseline (122.415 us; speedup 1.0000x reference)
//
#include <hip/hip_runtime.h>

#define N_POINTS  500000
#define K_CENT    512
#define W_DIM     64
#define N_TILES   (N_POINTS / 32)              // 15625 exact 32-point tiles
#define TPB_TILES 32                           // 16 pairs per block
#define N_BLOCKS  ((N_TILES + TPB_TILES - 1) / TPB_TILES)   // 489

typedef _Float16 half8 __attribute__((ext_vector_type(8)));
typedef float    f32x4 __attribute__((ext_vector_type(4)));

// ---- pre-kernel 1 (verbatim R20): codebook -> fragment-ordered f16 hi/lo of
// w=-2c. Layout [t:16][pl:2][cs:2][ks:2][lane:64][j:8]; cent c = t*32+cs*16+
// (l&15), dim d = ks*32+(l>>4)*8+j; lo = unscaled residual (REQUIRED, R19).
__global__ void cvt_kernel(const float* __restrict__ cb,
                           _Float16* __restrict__ cbf) {
    int id = blockIdx.x * 256 + threadIdx.x;           // 4096 ids
    if (id >= K_CENT * 8) return;
    int c = id >> 3, o = (id & 7) * 8;
    int t = c >> 5, csub = (c >> 4) & 1, r = c & 15;
    int kstep = o >> 5, grp = (o >> 3) & 3;
    int lane = grp * 16 + r;
    const float* src = cb + (size_t)c * W_DIM + o;
    half8 h, l;
#pragma unroll
    for (int j = 0; j < 8; ++j) {
        float w = -2.0f * src[j];
        _Float16 hh = (_Float16)w;                     // RNE
        h[j] = hh;
        l[j] = (_Float16)(w - (float)hh);
    }
    size_t bh = ((((size_t)t * 2 + 0) * 2 + csub) * 2 + kstep) * 512 + (size_t)lane * 8;
    size_t bl = ((((size_t)t * 2 + 1) * 2 + csub) * 2 + kstep) * 512 + (size_t)lane * 8;
    *(half8*)(cbf + bh) = h;
    *(half8*)(cbf + bl) = l;
}

// ---- pre-kernel 2 (verbatim): c2 in double
__global__ void c2_kernel(const float* __restrict__ cb, float* __restrict__ c2) {
    int c = blockIdx.x * 256 + threadIdx.x;
    if (c >= K_CENT) return;
    const float4* row = (const float4*)(cb + (size_t)c * W_DIM);
    double s = 0.0;
#pragma unroll
    for (int j = 0; j < W_DIM / 4; ++j) {
        float4 v = row[j];
        s += (double)v.x * v.x + (double)v.y * v.y + (double)v.z * v.z + (double)v.w * v.w;
    }
    c2[c] = (float)s;
}

#define MFMA16(A, B, C) __builtin_amdgcn_mfma_f32_16x16x32_f16(A, B, C, 0, 0, 0)

// Stage tile-PAIR (TB, TB+1) into Bbuf[BUF]: waves 0-7 only. Wave w stages
// slice (ps=(w&3)>>1, ks=w&1... w&3 decomposed) of tile TB+(w>>2). Lane =
// (gd=lane>>4, lp=lane&15): point p = ps*16+lp, dims ks*32+gd*8..+7 (two
// float4 = full 128B line, X read ONCE). half8 writes at seg*1024 + lane*16
// -> LINEAR in lane (conflict-free, R22-verified: 7M -> 125K).
#define STAGE_PAIR(TB, BUF, PR)                                                \
    if (wave < 8) {                                                            \
        int u_  = wave >> 2;                                                   \
        int w4  = wave & 3;                                                    \
        int ps_ = w4 >> 1, ks_ = w4 & 1;                                       \
        int gd_ = lane >> 4, lp_ = lane & 15;                                  \
        int p_  = ps_ * 16 + lp_;                                              \
        int t_  = (TB) + u_;                                                   \
        int tc_ = t_ < N_TILES ? t_ : (N_TILES - 1);                           \
        const float* xs = X + ((size_t)tc_ * 32 + p_) * W_DIM + ks_ * 32 + gd_ * 8; \
        float4 f0 = *(const float4*)xs, f1 = *(const float4*)(xs + 4);         \
        float fa[8] = {f0.x, f0.y, f0.z, f0.w, f1.x, f1.y, f1.z, f1.w};        \
        half8 hi, lo; float x2p = 0.f;                                         \
        _Pragma("unroll")                                                      \
        for (int j = 0; j < 8; ++j) {                                          \
            _Float16 hh = (_Float16)fa[j];                                     \
            hi[j] = hh;                                                        \
            lo[j] = (_Float16)(fa[j] - (float)hh);                             \
            x2p = fmaf(fa[j], fa[j], x2p);                                     \
        }                                                                      \
        int sh = ps_ * 4 + ks_;                                                \
        *(half8*)&Bbuf[BUF][u_][(sh + 0) * 512 + lane * 8] = hi;               \
        *(half8*)&Bbuf[BUF][u_][(sh + 2) * 512 + lane * 8] = lo;               \
        x2part[(PR) % 3][u_][ks_ * 4 + gd_][p_] = x2p;                         \
    }

// Compute ONE tile u of pair in Bbuf[BUF]: 8 x ds_read_b128 (linear), 24
// MFMAs = 4 chains (cs,ps) x 6-deep 3-term, C-in = q (c2, regs). Partial
// argmin over this wave's 32 cents -> part[BUF][u][wave].
#define COMPUTE_TILE(BUF, U)                                                   \
    {                                                                          \
        half8 bh[2][2], bl[2][2];                                              \
        _Pragma("unroll")                                                      \
        for (int ps = 0; ps < 2; ++ps)                                         \
            _Pragma("unroll")                                                  \
            for (int ks = 0; ks < 2; ++ks) {                                   \
                bh[ps][ks] = *(const half8*)&Bbuf[BUF][U][(ps * 4 + 0 + ks) * 512 + lane * 8]; \
                bl[ps][ks] = *(const half8*)&Bbuf[BUF][U][(ps * 4 + 2 + ks) * 512 + lane * 8]; \
            }                                                                  \
        f32x4 acc[2][2];                                                       \
        __builtin_amdgcn_s_setprio(1);                                         \
        _Pragma("unroll")                                                      \
        for (int cs = 0; cs < 2; ++cs)                                         \
            _Pragma("unroll")                                                  \
            for (int ps = 0; ps < 2; ++ps)                                     \
                acc[cs][ps] = MFMA16(aH[cs][0], bh[ps][0], q[cs]);             \
        _Pragma("unroll")                                                      \
        for (int cs = 0; cs < 2; ++cs)                                         \
            _Pragma("unroll")                                                  \
            for (int ps = 0; ps < 2; ++ps)                                     \
                acc[cs][ps] = MFMA16(aH[cs][1], bh[ps][1], acc[cs][ps]);       \
        _Pragma("unroll")                                                      \
        for (int cs = 0; cs < 2; ++cs)                                         \
            _Pragma("unroll")                                                  \
            for (int ps = 0; ps < 2; ++ps)                                     \
                acc[cs][ps] = MFMA16(aL[cs][0], bh[ps][0], acc[cs][ps]);       \
        _Pragma("unroll")                                                      \
        for (int cs = 0; cs < 2; ++cs)                                         \
            _Pragma("unroll")                                                  \
            for (int ps = 0; ps < 2; ++ps)                                     \
                acc[cs][ps] = MFMA16(aL[cs][1], bh[ps][1], acc[cs][ps]);       \
        _Pragma("unroll")                                                      \
        for (int cs = 0; cs < 2; ++cs)                                         \
            _Pragma("unroll")                                                  \
            for (int ps = 0; ps < 2; ++ps)                                     \
                acc[cs][ps] = MFMA16(aH[cs][0], bl[ps][0], acc[cs][ps]);       \
        _Pragma("unroll")                                                      \
        for (int cs = 0; cs < 2; ++cs)                                         \
            _Pragma("unroll")                                                  \
            for (int ps = 0; ps < 2; ++ps)                                     \
                acc[cs][ps] = MFMA16(aH[cs][1], bl[ps][1], acc[cs][ps]);       \
        __builtin_amdgcn_s_setprio(0);                                         \
        _Pragma("unroll")                                                      \
        for (int ps = 0; ps < 2; ++ps) {                                       \
            float v0 = acc[0][ps][0], v1 = acc[0][ps][1];                      \
            float v2 = acc[0][ps][2], v3 = acc[0][ps][3];                      \
            float v4 = acc[1][ps][0], v5 = acc[1][ps][1];                      \
            float v6 = acc[1][ps][2], v7 = acc[1][ps][3];                      \
            float a0 = fminf(v0, v1), a1 = fminf(v2, v3);                      \
            float a2 = fminf(v4, v5), a3 = fminf(v6, v7);                      \
            float b0 = fminf(a0, a1), b1 = fminf(a2, a3);                      \
            float m  = fminf(b0, b1);                                          \
            bool  L2 = (m == b0);                                              \
            float aLv = L2 ? a0 : a2;                                          \
            bool  L1 = (m == aLv);                                             \
            float vE = L2 ? (L1 ? v0 : v2) : (L1 ? v4 : v6);                   \
            bool  L0 = (m == vE);                                              \
            int ji = (L2 ? 0 : 4) | (L1 ? 0 : 2) | (L0 ? 0 : 1);               \
            int ci = wb + (ji >> 2) * 16 + grp4 + (ji & 3);                    \
            float bdp = m; int bip = ci;                                       \
            float od = __shfl_xor(bdp, 16); int oi = __shfl_xor(bip, 16);      \
            if (od < bdp || (od == bdp && oi < bip)) { bdp = od; bip = oi; }   \
            od = __shfl_xor(bdp, 32); oi = __shfl_xor(bip, 32);                \
            if (od < bdp || (od == bdp && oi < bip)) { bdp = od; bip = oi; }   \
            if (grp == 0) {                                                    \
                partd[BUF][U][wave][ps * 16 + l15] = bdp;                      \
                parti[BUF][U][wave][ps * 16 + l15] = (float)bip;               \
            }                                                                  \
        }                                                                      \
    }

// Combine pair (TB, TB+1): 64 threads (u = tid>>5, p = tid&31); merge the 16
// wave-partials ascending (explicit tie-break = global first-index since
// wave order = ascending centroid blocks); x2 = fixed-order sum of 8 slices.
#define COMBINE_PAIR(BUF, TB, PR)                                              \
    {                                                                          \
        if (tid < 64) {                                                        \
            int u_ = tid >> 5, p = tid & 31;                                   \
            int t_ = (TB) + u_;                                                \
            if (t_ < N_TILES) {                                                \
                float bdv = partd[BUF][u_][0][p];                              \
                float biv = parti[BUF][u_][0][p];                              \
                _Pragma("unroll")                                              \
                for (int w = 1; w < 16; ++w) {                                 \
                    float od = partd[BUF][u_][w][p], oi = parti[BUF][u_][w][p]; \
                    bool imp = (od < bdv) || (od == bdv && oi < biv);          \
                    bdv = imp ? od : bdv;                                      \
                    biv = imp ? oi : biv;                                      \
                }                                                              \
                float x2v = x2part[(PR) % 3][u_][0][p];                        \
                _Pragma("unroll")                                              \
                for (int w = 1; w < 8; ++w) x2v += x2part[(PR) % 3][u_][w][p]; \
                size_t pp = (size_t)t_ * 32 + p;                               \
                out_idx[pp]  = biv;                                            \
                out_dist[pp] = sqrtf(fmaxf(bdv + x2v, 0.f));                   \
            }                                                                  \
        }                                                                      \
    }

// ---- main kernel: CENTROIDS IN REGISTERS, POINTS STREAM. 16 waves/block,
// wave w holds cents [w*32,(w+1)*32) loaded ONCE (A-redelivery = 0). R25 vs
// R22/R23: per-wave demand ~92 unified regs << 128 cap from (1024,4) -> no
// spill, 4 waves/SIMD TLP; R22's conflict-free stage pattern.
__global__ __launch_bounds__(1024, 4)
void kmeans_mfma(const float* __restrict__ X,
                 const _Float16* __restrict__ cbf,
                 const float* __restrict__ c2,
                 float* __restrict__ out_idx,
                 float* __restrict__ out_dist) {
    __shared__ _Float16 Bbuf[2][2][4096];  // [pair-dbuf][tile][frag] 32 KB
    __shared__ float partd[2][2][16][32];  // [dbuf][tile][wave][pt] 8 KB
    __shared__ float parti[2][2][16][32];  // 8 KB
    __shared__ float x2part[3][2][8][32];  // [pair%3][tile][slice][pt] 6 KB

    int tid  = threadIdx.x;
    int wave = tid >> 6;                   // 0..15
    int lane = tid & 63;
    int l15  = lane & 15;
    int grp  = lane >> 4;
    int grp4 = grp * 4;
    int wb   = wave * 32;                  // this wave's centroid base

    // ---- load this wave's A-fragments (chunk = wave, 32 cents) ONCE
    half8 aH[2][2], aL[2][2];              // [cs][ks]
    f32x4 q[2];
#pragma unroll
    for (int cs = 0; cs < 2; ++cs) {
#pragma unroll
        for (int ks = 0; ks < 2; ++ks) {
            size_t bh_ = ((((size_t)wave * 2 + 0) * 2 + cs) * 2 + ks) * 512 + (size_t)lane * 8;
            size_t bl_ = ((((size_t)wave * 2 + 1) * 2 + cs) * 2 + ks) * 512 + (size_t)lane * 8;
            aH[cs][ks] = *(const half8*)(cbf + bh_);
            aL[cs][ks] = *(const half8*)(cbf + bl_);
        }
        q[cs] = *(const f32x4*)(c2 + wb + cs * 16 + grp4);
    }

    int t0 = blockIdx.x * TPB_TILES;
    int nt = N_TILES - t0; if (nt > TPB_TILES) nt = TPB_TILES;
    int npr = (nt + 1) >> 1;

    STAGE_PAIR(t0, 0, 0)
    __syncthreads();

#pragma unroll 1
    for (int pr = 0; pr < npr; ++pr) {
        int tb  = t0 + 2 * pr;
        int buf = pr & 1;
        if (pr + 1 < npr) STAGE_PAIR(tb + 2, buf ^ 1, pr + 1)
        COMPUTE_TILE(buf, 0)
        COMPUTE_TILE(buf, 1)
        if (pr > 0) COMBINE_PAIR((pr - 1) & 1, tb - 2, pr - 1)
        __syncthreads();
    }
    COMBINE_PAIR((npr - 1) & 1, t0 + 2 * (npr - 1), npr - 1)
}

extern "C" void kernel_launch(void* const* d_in, const int* in_sizes, int n_in,
                              void* d_out, int out_size, void* d_ws, size_t ws_size,
                              hipStream_t stream) {
    const float* X  = (const float*)d_in[0];
    const float* cb = (const float*)d_in[1];
    float* out      = (float*)d_out;

    // workspace: fragment-ordered codebook 128KB | c2 2KB
    _Float16* cbf = (_Float16*)d_ws;
    float*    c2  = (float*)(cbf + (size_t)K_CENT * W_DIM * 2);

    hipLaunchKernelGGL(cvt_kernel, dim3((K_CENT * 8 + 255) / 256), dim3(256), 0, stream, cb, cbf);
    hipLaunchKernelGGL(c2_kernel, dim3((K_CENT + 255) / 256), dim3(256), 0, stream, cb, c2);

    hipLaunchKernelGGL(kmeans_mfma, dim3(N_BLOCKS), dim3(1024), 0, stream,
                       X, cbf, c2, out, out + N_POINTS);
}

// Round 26
// 100.686 us; speedup vs baseline: 1.2158x; 1.2158x over previous
//
#include <hip/hip_runtime.h>

#define N_POINTS 500000
#define K_CENT   512
#define W_DIM    64
#define N_JOBS   (N_POINTS / 32)   // 15625 exact: 32 points per wave-job

typedef _Float16 half8 __attribute__((ext_vector_type(8)));
typedef float    f32x4 __attribute__((ext_vector_type(4)));

// ---- pre-kernel 1: codebook -> fragment-ordered f16 hi/lo of w=-2c.
// Layout: [t:16][plane:2][csub:2][kstep:2][lane:64][j:8] -> 8 KB/chunk,
// chunks contiguous (LDS DMA of PAIRS). cent c = t*32 + csub*16 + (l&15),
// dim d = kstep*32 + (l>>4)*8 + j. lo = unscaled residual. (Verified R11-R16;
// R19 proved the lo plane is REQUIRED: single-pass f16 flips argmin.)
__global__ void cvt_kernel(const float* __restrict__ cb,
                           _Float16* __restrict__ cbf) {
    int id = blockIdx.x * 256 + threadIdx.x;           // 4096 ids
    if (id >= K_CENT * 8) return;
    int c = id >> 3, o = (id & 7) * 8;                 // centroid, dim base
    int t = c >> 5, csub = (c >> 4) & 1, r = c & 15;
    int kstep = o >> 5, grp = (o >> 3) & 3;
    int lane = grp * 16 + r;
    const float* src = cb + (size_t)c * W_DIM + o;
    half8 h, l;
#pragma unroll
    for (int j = 0; j < 8; ++j) {
        float w = -2.0f * src[j];
        _Float16 hh = (_Float16)w;                     // RNE
        h[j] = hh;
        l[j] = (_Float16)(w - (float)hh);              // unscaled residual
    }
    size_t bh = ((((size_t)t * 2 + 0) * 2 + csub) * 2 + kstep) * 512 + (size_t)lane * 8;
    size_t bl = ((((size_t)t * 2 + 1) * 2 + csub) * 2 + kstep) * 512 + (size_t)lane * 8;
    *(half8*)(cbf + bh) = h;
    *(half8*)(cbf + bl) = l;
}

// ---- pre-kernel 2: c2[c] = ||c||^2 in double (deterministic, exact bias)
__global__ void c2_kernel(const float* __restrict__ cb, float* __restrict__ c2) {
    int c = blockIdx.x * 256 + threadIdx.x;
    if (c >= K_CENT) return;
    const float4* row = (const float4*)(cb + (size_t)c * W_DIM);
    double s = 0.0;
#pragma unroll
    for (int j = 0; j < W_DIM / 4; ++j) {
        float4 v = row[j];
        s += (double)v.x * v.x + (double)v.y * v.y + (double)v.z * v.z + (double)v.w * v.w;
    }
    c2[c] = (float)s;
}

#define MFMA16(A, B, C) __builtin_amdgcn_mfma_f32_16x16x32_f16(A, B, C, 0, 0, 0)

// Stage chunk PAIR (T, T+1) = 16 KB into abuf[BUF]; per wave 4 KB = 4 calls.
// LDS dest linear (wave-uniform base + lane*16); global src per-lane.
#define STAGE_PAIR(T, BUF)                                                     \
    {                                                                          \
        const __attribute__((address_space(1))) _Float16* g =                  \
            (const __attribute__((address_space(1))) _Float16*)                \
            (cbf + (size_t)(T) * 4096 + (size_t)wave * 2048 + (size_t)lane * 8); \
        __builtin_amdgcn_global_load_lds(                                      \
            (const __attribute__((address_space(1))) void*)g,                  \
            (__attribute__((address_space(3))) void*)&abuf[BUF][wave * 2048], 16, 0, 0); \
        __builtin_amdgcn_global_load_lds(                                      \
            (const __attribute__((address_space(1))) void*)(g + 512),          \
            (__attribute__((address_space(3))) void*)&abuf[BUF][wave * 2048 + 512], 16, 0, 0); \
        __builtin_amdgcn_global_load_lds(                                      \
            (const __attribute__((address_space(1))) void*)(g + 1024),         \
            (__attribute__((address_space(3))) void*)&abuf[BUF][wave * 2048 + 1024], 16, 0, 0); \
        __builtin_amdgcn_global_load_lds(                                      \
            (const __attribute__((address_space(1))) void*)(g + 1536),         \
            (__attribute__((address_space(3))) void*)&abuf[BUF][wave * 2048 + 1536], 16, 0, 0); \
    }

// 24 MFMAs for one chunk at half-buffer offset OFF within abuf[BUF]:
// 4 chains (cs,ps) x 6-deep 3-term (hi*hi ks0/ks1, lo_w*hi ks0/ks1,
// hi_w*lo ks0/ks1), C-in = Q0/Q1 (c2). Static offsets -> immediate LDS addrs.
#define MFMA_PHASE(BUF, OFF, ACC, Q0, Q1)                                      \
    {                                                                          \
        half8 aH[2][2], aL[2][2];                                              \
        _Pragma("unroll")                                                      \
        for (int cs = 0; cs < 2; ++cs)                                         \
            _Pragma("unroll")                                                  \
            for (int ks = 0; ks < 2; ++ks) {                                   \
                aH[cs][ks] = *(const half8*)&abuf[BUF][(OFF) + (cs * 2 + ks) * 512 + lane * 8]; \
                aL[cs][ks] = *(const half8*)&abuf[BUF][(OFF) + 2048 + (cs * 2 + ks) * 512 + lane * 8]; \
            }                                                                  \
        __builtin_amdgcn_s_setprio(1);                                         \
        _Pragma("unroll")                                                      \
        for (int cs = 0; cs < 2; ++cs)                                         \
            _Pragma("unroll")                                                  \
            for (int ps = 0; ps < 2; ++ps)                                     \
                ACC[cs][ps] = MFMA16(aH[cs][0], bh[ps][0], cs ? Q1 : Q0);      \
        _Pragma("unroll")                                                      \
        for (int cs = 0; cs < 2; ++cs)                                         \
            _Pragma("unroll")                                                  \
            for (int ps = 0; ps < 2; ++ps)                                     \
                ACC[cs][ps] = MFMA16(aH[cs][1], bh[ps][1], ACC[cs][ps]);       \
        _Pragma("unroll")                                                      \
        for (int cs = 0; cs < 2; ++cs)                                         \
            _Pragma("unroll")                                                  \
            for (int ps = 0; ps < 2; ++ps)                                     \
                ACC[cs][ps] = MFMA16(aL[cs][0], bh[ps][0], ACC[cs][ps]);       \
        _Pragma("unroll")                                                      \
        for (int cs = 0; cs < 2; ++cs)                                         \
            _Pragma("unroll")                                                  \
            for (int ps = 0; ps < 2; ++ps)                                     \
                ACC[cs][ps] = MFMA16(aL[cs][1], bh[ps][1], ACC[cs][ps]);       \
        _Pragma("unroll")                                                      \
        for (int cs = 0; cs < 2; ++cs)                                         \
            _Pragma("unroll")                                                  \
            for (int ps = 0; ps < 2; ++ps)                                     \
                ACC[cs][ps] = MFMA16(aH[cs][0], bl[ps][0], ACC[cs][ps]);       \
        _Pragma("unroll")                                                      \
        for (int cs = 0; cs < 2; ++cs)                                         \
            _Pragma("unroll")                                                  \
            for (int ps = 0; ps < 2; ++ps)                                     \
                ACC[cs][ps] = MFMA16(aH[cs][1], bl[ps][1], ACC[cs][ps]);       \
        __builtin_amdgcn_s_setprio(0);                                         \
    }

// 16-value argmin per chunk-PAIR (TA, TA+1): v0..7 = accP, v8..15 = accQ.
// Tree (prefer-left) + binary descent; order-independent via explicit
// (m==bd && ci<bi) tie-break; ci monotone in ji within the pair.
#define PAIR_ARGMIN(TA)                                                        \
    {                                                                          \
        _Pragma("unroll")                                                      \
        for (int ps = 0; ps < 2; ++ps) {                                       \
            float v0 = accP[0][ps][0], v1 = accP[0][ps][1];                    \
            float v2 = accP[0][ps][2], v3 = accP[0][ps][3];                    \
            float v4 = accP[1][ps][0], v5 = accP[1][ps][1];                    \
            float v6 = accP[1][ps][2], v7 = accP[1][ps][3];                    \
            float v8 = accQ[0][ps][0], v9 = accQ[0][ps][1];                    \
            float v10 = accQ[0][ps][2], v11 = accQ[0][ps][3];                  \
            float v12 = accQ[1][ps][0], v13 = accQ[1][ps][1];                  \
            float v14 = accQ[1][ps][2], v15 = accQ[1][ps][3];                  \
            float a0 = fminf(v0, v1),   a1 = fminf(v2, v3);                    \
            float a2 = fminf(v4, v5),   a3 = fminf(v6, v7);                    \
            float a4 = fminf(v8, v9),   a5 = fminf(v10, v11);                  \
            float a6 = fminf(v12, v13), a7 = fminf(v14, v15);                  \
            float b0 = fminf(a0, a1), b1 = fminf(a2, a3);                      \
            float b2 = fminf(a4, a5), b3 = fminf(a6, a7);                      \
            float c0 = fminf(b0, b1), c1 = fminf(b2, b3);                      \
            float m  = fminf(c0, c1);                                          \
            bool  L3 = (m == c0);                                              \
            float bL = L3 ? b0 : b2;                                           \
            bool  L2 = (m == bL);                                              \
            float aL = L3 ? (L2 ? a0 : a2) : (L2 ? a4 : a6);                   \
            bool  L1 = (m == aL);                                              \
            float vE = L3 ? (L2 ? (L1 ? v0 : v2) : (L1 ? v4 : v6))             \
                          : (L2 ? (L1 ? v8 : v10) : (L1 ? v12 : v14));         \
            bool  L0 = (m == vE);                                              \
            int ji = (L3 ? 0 : 8) | (L2 ? 0 : 4) | (L1 ? 0 : 2) | (L0 ? 0 : 1); \
            int jj = ji & 7;                                                   \
            int ci = ((TA) + (ji >> 3)) * 32 + (jj >> 2) * 16 + grp4 + (jj & 3); \
            bool imp = (m < bd[ps]) || (m == bd[ps] && ci < bi[ps]);           \
            bd[ps] = imp ? m : bd[ps];                                         \
            bi[ps] = imp ? ci : bi[ps];                                        \
        }                                                                      \
    }

// ---- main kernel: R16 structure with PAIR staging -> ONE barrier per
// chunk-pair (8/sweep vs 16). 4 waves/block, 32 points/wave, rotation.
__global__ __launch_bounds__(256, 2)
void kmeans_mfma(const float* __restrict__ X,
                 const _Float16* __restrict__ cbf,
                 const float* __restrict__ c2,
                 float* __restrict__ out_idx,
                 float* __restrict__ out_dist) {
    __shared__ _Float16 abuf[2][8192];     // 2 x 16 KB pair double buffer
    __shared__ float c2s[K_CENT];          // 2 KB   (total 34 KB -> 4 blk/CU)
    int tid = threadIdx.x;
    c2s[tid] = c2[tid];
    c2s[tid + 256] = c2[tid + 256];

    int wave = tid >> 6;
    int lane = tid & 63;
    int l15  = lane & 15;
    int grp  = lane >> 4;        // 0..3
    int grp4 = grp * 4;
    int grp8 = grp * 8;
    int rot  = (blockIdx.x & 7) * 2;   // even rotation: pairs never wrap

    int job   = blockIdx.x * 4 + wave;
    int valid = job < N_JOBS;
    int jc    = valid ? job : (N_JOBS - 1);   // invalid waves still hit barriers

    // ---- load + convert X: 2 point-subtiles x 2 K-steps, f16 hi + lo
    half8 bh[2][2], bl[2][2];
    float x2[2] = {0.f, 0.f};
#pragma unroll
    for (int ps = 0; ps < 2; ++ps) {
        int p = jc * 32 + ps * 16 + l15;
#pragma unroll
        for (int ks = 0; ks < 2; ++ks) {
            const float4* xp = (const float4*)(X + (size_t)p * W_DIM + ks * 32 + grp8);
            float4 f0 = xp[0], f1 = xp[1];
            float fa[8] = {f0.x, f0.y, f0.z, f0.w, f1.x, f1.y, f1.z, f1.w};
#pragma unroll
            for (int j = 0; j < 8; ++j) {
                _Float16 hh = (_Float16)fa[j];
                bh[ps][ks][j] = hh;
                bl[ps][ks][j] = (_Float16)(fa[j] - (float)hh);
                x2[ps] = fmaf(fa[j], fa[j], x2[ps]);
            }
        }
    }
#pragma unroll
    for (int ps = 0; ps < 2; ++ps) {    // full ||x||^2 across the 4 row-groups
        x2[ps] += __shfl_xor(x2[ps], 16);
        x2[ps] += __shfl_xor(x2[ps], 32);
    }

    float bd[2] = {3.4e38f, 3.4e38f};
    int   bi[2] = {0, 0};
    f32x4 accP[2][2], accQ[2][2];

    STAGE_PAIR(rot, 0)
    __syncthreads();    // drains vmcnt -> abuf[0] pair + c2s ready

#pragma unroll 1
    for (int it = 0; it < 8; ++it) {
        int ta = (rot + 2 * it) & 15;   // even; pair (ta, ta+1), no wrap
        int b  = it & 1;
        // stage NEXT pair into the other buffer (async, in flight during MFMAs)
        if (it < 7) {
            int tn = (ta + 2) & 15;
            STAGE_PAIR(tn, b ^ 1)
        }
        f32x4 qa0 = *(const f32x4*)&c2s[ta * 32 + grp4];
        f32x4 qa1 = *(const f32x4*)&c2s[ta * 32 + 16 + grp4];
        f32x4 qb0 = *(const f32x4*)&c2s[ta * 32 + 32 + grp4];
        f32x4 qb1 = *(const f32x4*)&c2s[ta * 32 + 48 + grp4];
        MFMA_PHASE(b, 0,    accP, qa0, qa1)      // chunk ta
        MFMA_PHASE(b, 4096, accQ, qb0, qb1)      // chunk ta+1
        PAIR_ARGMIN(ta)
        __syncthreads();   // next pair staged everywhere; this buffer free
    }

    // cross-lane combine over the 4 row-groups (disjoint cents per group);
    // explicit lower-index preference on fp-equal ties.
#pragma unroll
    for (int ps = 0; ps < 2; ++ps) {
        float od = __shfl_xor(bd[ps], 16); int oi = __shfl_xor(bi[ps], 16);
        if (od < bd[ps] || (od == bd[ps] && oi < bi[ps])) { bd[ps] = od; bi[ps] = oi; }
        od = __shfl_xor(bd[ps], 32); oi = __shfl_xor(bi[ps], 32);
        if (od < bd[ps] || (od == bd[ps] && oi < bi[ps])) { bd[ps] = od; bi[ps] = oi; }
    }

    if (valid && grp == 0) {
#pragma unroll
        for (int ps = 0; ps < 2; ++ps) {
            int p = jc * 32 + ps * 16 + l15;
            out_idx[p]  = (float)bi[ps];
            out_dist[p] = sqrtf(fmaxf(bd[ps] + x2[ps], 0.f));
        }
    }
}

extern "C" void kernel_launch(void* const* d_in, const int* in_sizes, int n_in,
                              void* d_out, int out_size, void* d_ws, size_t ws_size,
                              hipStream_t stream) {
    const float* X  = (const float*)d_in[0];
    const float* cb = (const float*)d_in[1];
    float* out      = (float*)d_out;

    // workspace: fragment-ordered codebook 128KB | c2 2KB
    _Float16* cbf = (_Float16*)d_ws;
    float*    c2  = (float*)(cbf + (size_t)K_CENT * W_DIM * 2);

    hipLaunchKernelGGL(cvt_kernel, dim3((K_CENT * 8 + 255) / 256), dim3(256), 0, stream, cb, cbf);
    hipLaunchKernelGGL(c2_kernel, dim3((K_CENT + 255) / 256), dim3(256), 0, stream, cb, c2);

    hipLaunchKernelGGL(kmeans_mfma, dim3((N_JOBS + 3) / 4), dim3(256), 0, stream,
                       X, cbf, c2, out, out + N_POINTS);
}